// Round 8
// baseline (76.077 us; speedup 1.0000x reference)
//
#include <hip/hip_runtime.h>
#include <float.h>

// x: [B=32][C=3][L=8192] f32, weight: [O=128][C=3][K=64] f32
// out[b][o] = -2 * max_t ( conv(b,o,t) - ||w_o||^2/2 - ||win_{b,t}||^2/2 ), t in [0, 8129)
#define BB 32
#define LL 8192
#define OO 128
#define KK 64
#define WW (LL - KK + 1)   // 8129
#define NCH 4              // t-chunks of 256 per block
#define GX 8               // 8*4*256 = 8192 t covered

typedef __attribute__((ext_vector_type(8))) short short8;
typedef __attribute__((ext_vector_type(4))) float f32x4;

union AB { int4 i4; int i[4]; short8 v; };

static __device__ __forceinline__ unsigned int f2bf(float f) {
    unsigned int u = __builtin_bit_cast(unsigned int, f);
    return (u + 0x7FFFu + ((u >> 16) & 1u)) >> 16;   // RNE
}

// ---- prep: W -> bf16 swizzled into A-fragment order; wn[o] = ||w_o||^2/2 ----
// wswz 16B-chunk idx (per ob half of 1536): (ks*4+qp)*64 + o_local; chunk =
// w[o][c*64 + h*32 + qp*8 .. +8) bf16, ks = 2c+h.
__global__ __launch_bounds__(256) void prep_kernel(const float* __restrict__ w,
                                                   unsigned short* __restrict__ wswz,
                                                   float* __restrict__ wn) {
    int g = blockIdx.x * 256 + threadIdx.x;
    if (g < 3072) {
        int ob = (g >= 1536) ? 1 : 0;
        int gg = g - ob * 1536;
        int ksqp = gg >> 6;
        int o2   = gg & 63;
        int ks = ksqp >> 2, qp = ksqp & 3;
        int c = ks >> 1, h = ks & 1;
        const float4* p = (const float4*)(w + (ob * 64 + o2) * 192 + c * 64 + h * 32 + qp * 8);
        float4 v0 = p[0], v1 = p[1];
        int4 pk;
        pk.x = (int)(f2bf(v0.x) | (f2bf(v0.y) << 16));
        pk.y = (int)(f2bf(v0.z) | (f2bf(v0.w) << 16));
        pk.z = (int)(f2bf(v1.x) | (f2bf(v1.y) << 16));
        pk.w = (int)(f2bf(v1.z) | (f2bf(v1.w) << 16));
        ((int4*)wswz)[g] = pk;
    }
    int oo = g - 3072;
    if (oo >= 0 && oo < OO) {
        const float* p = w + oo * 192;
        float s = 0.f;
        for (int i = 0; i < 192; ++i) { float v = p[i]; s = fmaf(v, v, s); }
        wn[oo] = 0.5f * s;
    }
}

// Stage chunk: x bf16 tile + sq (fp32) + P8 partials (via shfl butterfly).
static __device__ __forceinline__ void stage_chunk(const float* __restrict__ x, int b, int T0,
                                                   unsigned short* xl, float* sql, float* Pl,
                                                   int tid) {
    if (tid < 240) {
        int c = tid / 80, j4 = tid - c * 80;
        int l = T0 + j4 * 4;
        float4 v = make_float4(0.f, 0.f, 0.f, 0.f);
        if (l < LL) v = *(const float4*)(x + (b * 3 + c) * LL + l);
        uint2 pk;
        pk.x = f2bf(v.x) | (f2bf(v.y) << 16);
        pk.y = f2bf(v.z) | (f2bf(v.w) << 16);
        *(uint2*)(xl + c * 320 + j4 * 4) = pk;
    }
    {
        int l = T0 + tid;
        float s = 0.f;
        if (l < LL) {
            #pragma unroll
            for (int c = 0; c < 3; ++c) {
                float v = x[(b * 3 + c) * LL + l];
                s = fmaf(v, v, s);
            }
        }
        sql[tid] = s;
        float s8 = s + __shfl_xor(s, 1, 64);
        s8 += __shfl_xor(s8, 2, 64);
        s8 += __shfl_xor(s8, 4, 64);
        if ((tid & 7) == 0) Pl[tid >> 3] = s8;
    }
    if (tid < 64) {
        int j = 256 + tid, l = T0 + j;
        float s = 0.f;
        if (l < LL) {
            #pragma unroll
            for (int c = 0; c < 3; ++c) {
                float v = x[(b * 3 + c) * LL + l];
                s = fmaf(v, v, s);
            }
        }
        sql[j] = s;
        float s8 = s + __shfl_xor(s, 1, 64);
        s8 += __shfl_xor(s8, 2, 64);
        s8 += __shfl_xor(s8, 4, 64);
        if ((tid & 7) == 0) Pl[32 + (tid >> 3)] = s8;
    }
}

// ---- main: grid (8 tcx, 2 ob, 32 b) = 512 blocks, 4 waves, 4 chunks/block ----
// Wave (wo=wv&1, wt=wv>>1): o in [64ob+32wo, +32), t = T0 + 128wt + r + 8n.
// A-fragments + wn + win all register-resident; one barrier per chunk.
__global__ __launch_bounds__(256, 2) void shapeconv_main(const float* __restrict__ x,
                                                         const unsigned short* __restrict__ wswz,
                                                         const float* __restrict__ wn,
                                                         float* __restrict__ partial) {
    __shared__ __align__(16) unsigned short x_lds[2][3 * 320];
    __shared__ __align__(16) float sq_lds[2][320];
    __shared__ float P_lds[2][40];
    __shared__ float mred[64];

    const int tcx = blockIdx.x;
    const int ob = blockIdx.y;
    const int b  = blockIdx.z;
    const int tid = threadIdx.x;
    const int wv = tid >> 6;
    const int lane = tid & 63;
    const int wo = wv & 1, wt = wv >> 1;
    const int n  = lane & 15;
    const int qp = lane >> 4;
    const int Tb = tcx * (NCH * 256);

    // A-fragments once per block, straight from L2-hot wswz (issued first; latency
    // overlaps the first staging below). 12 x 16B per thread = 48 VGPRs held.
    AB afr[2][6];
    #pragma unroll
    for (int ot = 0; ot < 2; ++ot)
        #pragma unroll
        for (int ks = 0; ks < 6; ++ks)
            afr[ot][ks].i4 = ((const int4*)wswz)[ob * 1536 + (ks * 4 + qp) * 64 + 32 * wo + 16 * ot + n];

    // wn values for this lane's 8 output rows (broadcast-heavy, L1)
    float wnv[2][4];
    #pragma unroll
    for (int ot = 0; ot < 2; ++ot)
        #pragma unroll
        for (int rg = 0; rg < 4; ++rg)
            wnv[ot][rg] = wn[ob * 64 + 32 * wo + 16 * ot + 4 * qp + rg];

    stage_chunk(x, b, Tb, x_lds[0], sq_lds[0], P_lds[0], tid);

    float m2[2][4];
    #pragma unroll
    for (int ot = 0; ot < 2; ++ot)
        #pragma unroll
        for (int rg = 0; rg < 4; ++rg) m2[ot][rg] = -FLT_MAX;

    #pragma unroll
    for (int ci = 0; ci < NCH; ++ci) {
        const int bsel = ci & 1;
        const int T0 = Tb + ci * 256;
        __syncthreads();   // staging(ci) visible; prev chunk's readers done

        // issue next chunk's staging first: its global loads fly behind win+K-loop
        if (ci + 1 < NCH)
            stage_chunk(x, b, T0 + 256, x_lds[1 - bsel], sq_lds[1 - bsel], P_lds[1 - bsel], tid);

        // win in registers: lane's 8 t are consecutive [8a, 8a+8), a = 16wt+n.
        // s_r = sum P[a+1..a+7] + sum_{j>=r} h[j] + sum_{j<r} g[j]; slide with -h[r]+g[r].
        float wlm[8];
        {
            const float* sql = sq_lds[bsel];
            const float* Pl  = P_lds[bsel];
            int a = 16 * wt + n;
            float4 H0 = *(const float4*)(sql + 8 * a);
            float4 H1 = *(const float4*)(sql + 8 * a + 4);
            float4 G0 = *(const float4*)(sql + 8 * a + 64);
            float4 G1 = *(const float4*)(sql + 8 * a + 68);
            float h[8] = {H0.x, H0.y, H0.z, H0.w, H1.x, H1.y, H1.z, H1.w};
            float g[8] = {G0.x, G0.y, G0.z, G0.w, G1.x, G1.y, G1.z, G1.w};
            float s = 0.f;
            #pragma unroll
            for (int i = 1; i <= 7; ++i) s += Pl[a + i];
            #pragma unroll
            for (int j = 0; j < 8; ++j) s += h[j];
            int tg0 = T0 + 8 * a;
            #pragma unroll
            for (int r = 0; r < 8; ++r) {
                wlm[r] = (tg0 + r < WW) ? 0.5f * s : 1e30f;
                s = s - h[r] + g[r];
            }
        }

        // acc init with -(wn + win)
        f32x4 acc[2][8];
        #pragma unroll
        for (int ot = 0; ot < 2; ++ot)
            #pragma unroll
            for (int rg = 0; rg < 4; ++rg)
                #pragma unroll
                for (int r = 0; r < 8; ++r)
                    acc[ot][r][rg] = -wnv[ot][rg] - wlm[r];

        // K-loop: 6 ks x 8 r x 2 ot = 96 MFMAs/wave; only x comes from LDS now
        const char* xb = (const char*)x_lds[bsel];
        #pragma unroll
        for (int ks = 0; ks < 6; ++ks) {
            int c = ks >> 1, h2 = ks & 1;
            int e0b = c * 640 + 256 * wt + 64 * h2 + 16 * (n + qp);
            int4 Ea = *(const int4*)(xb + e0b);
            int4 Eb = *(const int4*)(xb + e0b + 16);
            int D[8] = {Ea.x, Ea.y, Ea.z, Ea.w, Eb.x, Eb.y, Eb.z, Eb.w};
            #pragma unroll
            for (int r = 0; r < 8; ++r) {
                AB bf;
                int s = r >> 1;
                if ((r & 1) == 0) {
                    bf.i[0] = D[s]; bf.i[1] = D[s + 1]; bf.i[2] = D[s + 2]; bf.i[3] = D[s + 3];
                } else {
                    #pragma unroll
                    for (int d = 0; d < 4; ++d)
                        bf.i[d] = (int)(((unsigned)D[s + d] >> 16) | ((unsigned)D[s + d + 1] << 16));
                }
                acc[0][r] = __builtin_amdgcn_mfma_f32_16x16x32_bf16(afr[0][ks].v, bf.v, acc[0][r], 0, 0, 0);
                acc[1][r] = __builtin_amdgcn_mfma_f32_16x16x32_bf16(afr[1][ks].v, bf.v, acc[1][r], 0, 0, 0);
            }
        }

        // per-chunk register max
        #pragma unroll
        for (int ot = 0; ot < 2; ++ot)
            #pragma unroll
            for (int rg = 0; rg < 4; ++rg) {
                float mm = m2[ot][rg];
                #pragma unroll
                for (int r = 0; r < 8; ++r) mm = fmaxf(mm, acc[ot][r][rg]);
                m2[ot][rg] = mm;
            }
    }

    // cross-lane max over n -> wt-pair combine -> dump
    #pragma unroll
    for (int s = 1; s <= 8; s <<= 1)
        #pragma unroll
        for (int ot = 0; ot < 2; ++ot)
            #pragma unroll
            for (int rg = 0; rg < 4; ++rg)
                m2[ot][rg] = fmaxf(m2[ot][rg], __shfl_xor(m2[ot][rg], s, 64));

    if (wt == 1 && n == 0) {
        #pragma unroll
        for (int ot = 0; ot < 2; ++ot)
            #pragma unroll
            for (int rg = 0; rg < 4; ++rg)
                mred[32 * wo + 16 * ot + 4 * qp + rg] = m2[ot][rg];
    }
    __syncthreads();
    if (wt == 0 && n == 0) {
        #pragma unroll
        for (int ot = 0; ot < 2; ++ot)
            #pragma unroll
            for (int rg = 0; rg < 4; ++rg) {
                int oi = 32 * wo + 16 * ot + 4 * qp + rg;
                float v = fmaxf(m2[ot][rg], mred[oi]);
                partial[((size_t)(b * GX + tcx) * 2 + ob) * 64 + oi] = v;
            }
    }
}

// max over the 8 tcx chunks, scale by -2
__global__ __launch_bounds__(256) void reduce_kernel(const float* __restrict__ partial,
                                                     float* __restrict__ out) {
    int idx = blockIdx.x * 256 + threadIdx.x;   // 4096 = 32*128
    int b = idx >> 7, o = idx & 127;
    const float* pp = partial + ((size_t)b * GX * 2 + (o >> 6)) * 64 + (o & 63);
    float mx = -FLT_MAX;
    #pragma unroll
    for (int t = 0; t < GX; ++t) mx = fmaxf(mx, pp[(size_t)t * 128]);
    out[idx] = -2.f * mx;
}

extern "C" void kernel_launch(void* const* d_in, const int* in_sizes, int n_in,
                              void* d_out, int out_size, void* d_ws, size_t ws_size,
                              hipStream_t stream) {
    const float* x = (const float*)d_in[0];   // [32][3][8192]
    const float* w = (const float*)d_in[1];   // [128][3][64]
    float* out = (float*)d_out;               // [32][128]

    // ws: wswz bf16 swizzled [3072 x 16B] | wn f32 [128] | partial f32 [32][8][2][64]
    unsigned short* wswz = (unsigned short*)d_ws;
    float* wn = (float*)((char*)d_ws + 49152);
    float* partial = (float*)((char*)d_ws + 49664);

    prep_kernel<<<13, 256, 0, stream>>>(w, wswz, wn);
    dim3 grid(GX, 2, BB);                     // 512 blocks, 4 chunks each
    shapeconv_main<<<grid, 256, 0, stream>>>(x, wswz, wn, partial);
    reduce_kernel<<<16, 256, 0, stream>>>(partial, out);
}

// Round 9
// 75.081 us; speedup vs baseline: 1.0133x; 1.0133x over previous
//
#include <hip/hip_runtime.h>
#include <float.h>

// x: [B=32][C=3][L=8192] f32, weight: [O=128][C=3][K=64] f32
// out[b][o] = -2 * max_t ( conv(b,o,t) - ||w_o||^2/2 - ||win_{b,t}||^2/2 ), t in [0, 8129)
#define BB 32
#define LL 8192
#define OO 128
#define KK 64
#define WW (LL - KK + 1)   // 8129
#define NCH 2              // t-chunks of 256 per block
#define GX 16              // 16*2*256 = 8192 t covered

typedef __attribute__((ext_vector_type(8))) short short8;
typedef __attribute__((ext_vector_type(4))) float f32x4;

union AB { int4 i4; int i[4]; short8 v; };

static __device__ __forceinline__ unsigned int f2bf(float f) {
    unsigned int u = __builtin_bit_cast(unsigned int, f);
    return (u + 0x7FFFu + ((u >> 16) & 1u)) >> 16;   // RNE
}

// ---- prep: W -> bf16 swizzled into A-fragment order; wn[o] = ||w_o||^2/2 ----
// wswz 16B-chunk idx (per ob half of 1536): (ks*4+qp)*64 + o_local; chunk =
// w[o][c*64 + h*32 + qp*8 .. +8) bf16, ks = 2c+h.
__global__ __launch_bounds__(256) void prep_kernel(const float* __restrict__ w,
                                                   unsigned short* __restrict__ wswz,
                                                   float* __restrict__ wn) {
    int g = blockIdx.x * 256 + threadIdx.x;
    if (g < 3072) {
        int ob = (g >= 1536) ? 1 : 0;
        int gg = g - ob * 1536;
        int ksqp = gg >> 6;
        int o2   = gg & 63;
        int ks = ksqp >> 2, qp = ksqp & 3;
        int c = ks >> 1, h = ks & 1;
        const float4* p = (const float4*)(w + (ob * 64 + o2) * 192 + c * 64 + h * 32 + qp * 8);
        float4 v0 = p[0], v1 = p[1];
        int4 pk;
        pk.x = (int)(f2bf(v0.x) | (f2bf(v0.y) << 16));
        pk.y = (int)(f2bf(v0.z) | (f2bf(v0.w) << 16));
        pk.z = (int)(f2bf(v1.x) | (f2bf(v1.y) << 16));
        pk.w = (int)(f2bf(v1.z) | (f2bf(v1.w) << 16));
        ((int4*)wswz)[g] = pk;
    }
    int oo = g - 3072;
    if (oo >= 0 && oo < OO) {
        const float* p = w + oo * 192;
        float s = 0.f;
        for (int i = 0; i < 192; ++i) { float v = p[i]; s = fmaf(v, v, s); }
        wn[oo] = 0.5f * s;
    }
}

// Stage chunk: x bf16 tile + sq (fp32) + P8 partials (via shfl butterfly).
static __device__ __forceinline__ void stage_chunk(const float* __restrict__ x, int b, int T0,
                                                   unsigned short* xl, float* sql, float* Pl,
                                                   int tid) {
    if (tid < 240) {
        int c = tid / 80, j4 = tid - c * 80;
        int l = T0 + j4 * 4;
        float4 v = make_float4(0.f, 0.f, 0.f, 0.f);
        if (l < LL) v = *(const float4*)(x + (b * 3 + c) * LL + l);
        uint2 pk;
        pk.x = f2bf(v.x) | (f2bf(v.y) << 16);
        pk.y = f2bf(v.z) | (f2bf(v.w) << 16);
        *(uint2*)(xl + c * 320 + j4 * 4) = pk;
    }
    {
        int l = T0 + tid;
        float s = 0.f;
        if (l < LL) {
            #pragma unroll
            for (int c = 0; c < 3; ++c) {
                float v = x[(b * 3 + c) * LL + l];
                s = fmaf(v, v, s);
            }
        }
        sql[tid] = s;
        float s8 = s + __shfl_xor(s, 1, 64);
        s8 += __shfl_xor(s8, 2, 64);
        s8 += __shfl_xor(s8, 4, 64);
        if ((tid & 7) == 0) Pl[tid >> 3] = s8;
    }
    if (tid < 64) {
        int j = 256 + tid, l = T0 + j;
        float s = 0.f;
        if (l < LL) {
            #pragma unroll
            for (int c = 0; c < 3; ++c) {
                float v = x[(b * 3 + c) * LL + l];
                s = fmaf(v, v, s);
            }
        }
        sql[j] = s;
        float s8 = s + __shfl_xor(s, 1, 64);
        s8 += __shfl_xor(s8, 2, 64);
        s8 += __shfl_xor(s8, 4, 64);
        if ((tid & 7) == 0) Pl[32 + (tid >> 3)] = s8;
    }
}

// ---- main: grid (16 tcx, 2 ob, 32 b) = 1024 blocks, 4 waves, 2 chunks/block ----
// Wave (wo=wv&1, wt=wv>>1): o in [64ob+32wo, +32), t = T0 + 128wt + r + 8n.
// A-fragments from LDS (frees ~48 VGPRs); win in registers (no B2 barrier);
// launch_bounds(256,3) -> 3 blocks/CU, 3 waves/SIMD for latency hiding.
__global__ __launch_bounds__(256, 3) void shapeconv_main(const float* __restrict__ x,
                                                         const unsigned short* __restrict__ wswz,
                                                         const float* __restrict__ wn,
                                                         float* __restrict__ partial) {
    __shared__ __align__(16) unsigned short w_lds[64 * 192];     // 24576 B swizzled
    __shared__ __align__(16) unsigned short x_lds[2][3 * 320];
    __shared__ __align__(16) float sq_lds[2][320];
    __shared__ float P_lds[2][40];
    __shared__ float mred[64];

    const int tcx = blockIdx.x;
    const int ob = blockIdx.y;
    const int b  = blockIdx.z;
    const int tid = threadIdx.x;
    const int wv = tid >> 6;
    const int lane = tid & 63;
    const int wo = wv & 1, wt = wv >> 1;
    const int n  = lane & 15;
    const int qp = lane >> 4;
    const int Tb = tcx * (NCH * 256);

    // W stage once per block: async global->LDS width 16, linear layout
    {
        const char* src = (const char*)(wswz + ob * 1536 * 8) + tid * 16;
        #pragma unroll
        for (int i = 0; i < 6; ++i) {
            __builtin_amdgcn_global_load_lds(
                (const __attribute__((address_space(1))) unsigned int*)(src + i * 4096),
                (__attribute__((address_space(3))) unsigned int*)((char*)w_lds + wv * 1024 + i * 4096),
                16, 0, 0);
        }
    }

    // wn values for this lane's 8 output rows (broadcast-heavy, L1/L2-hot)
    float wnv[2][4];
    #pragma unroll
    for (int ot = 0; ot < 2; ++ot)
        #pragma unroll
        for (int rg = 0; rg < 4; ++rg)
            wnv[ot][rg] = wn[ob * 64 + 32 * wo + 16 * ot + 4 * qp + rg];

    stage_chunk(x, b, Tb, x_lds[0], sq_lds[0], P_lds[0], tid);

    float m2[2][4];
    #pragma unroll
    for (int ot = 0; ot < 2; ++ot)
        #pragma unroll
        for (int rg = 0; rg < 4; ++rg) m2[ot][rg] = -FLT_MAX;

    #pragma unroll
    for (int ci = 0; ci < NCH; ++ci) {
        const int bsel = ci & 1;
        const int T0 = Tb + ci * 256;
        __syncthreads();   // staging(ci) + (ci==0: W DMA) visible

        // issue next chunk's staging first: its global loads fly behind win+K-loop
        if (ci + 1 < NCH)
            stage_chunk(x, b, T0 + 256, x_lds[1 - bsel], sq_lds[1 - bsel], P_lds[1 - bsel], tid);

        // win in registers: lane's 8 t are consecutive [8a, 8a+8), a = 16wt+n.
        float wlm[8];
        {
            const float* sql = sq_lds[bsel];
            const float* Pl  = P_lds[bsel];
            int a = 16 * wt + n;
            float4 H0 = *(const float4*)(sql + 8 * a);
            float4 H1 = *(const float4*)(sql + 8 * a + 4);
            float4 G0 = *(const float4*)(sql + 8 * a + 64);
            float4 G1 = *(const float4*)(sql + 8 * a + 68);
            float h[8] = {H0.x, H0.y, H0.z, H0.w, H1.x, H1.y, H1.z, H1.w};
            float g[8] = {G0.x, G0.y, G0.z, G0.w, G1.x, G1.y, G1.z, G1.w};
            float s = 0.f;
            #pragma unroll
            for (int i = 1; i <= 7; ++i) s += Pl[a + i];
            #pragma unroll
            for (int j = 0; j < 8; ++j) s += h[j];
            int tg0 = T0 + 8 * a;
            #pragma unroll
            for (int r = 0; r < 8; ++r) {
                wlm[r] = (tg0 + r < WW) ? 0.5f * s : 1e30f;
                s = s - h[r] + g[r];
            }
        }

        // acc init with -(wn + win)
        f32x4 acc[2][8];
        #pragma unroll
        for (int ot = 0; ot < 2; ++ot)
            #pragma unroll
            for (int rg = 0; rg < 4; ++rg)
                #pragma unroll
                for (int r = 0; r < 8; ++r)
                    acc[ot][r][rg] = -wnv[ot][rg] - wlm[r];

        // K-loop: 6 ks x 8 r x 2 ot = 96 MFMAs/wave; A-frags from LDS
        const char* xb = (const char*)x_lds[bsel];
        #pragma unroll
        for (int ks = 0; ks < 6; ++ks) {
            int c = ks >> 1, h2 = ks & 1;
            int e0b = c * 640 + 256 * wt + 64 * h2 + 16 * (n + qp);
            int4 Ea = *(const int4*)(xb + e0b);
            int4 Eb = *(const int4*)(xb + e0b + 16);
            int D[8] = {Ea.x, Ea.y, Ea.z, Ea.w, Eb.x, Eb.y, Eb.z, Eb.w};
            AB a0, a1;
            const int4* wq = (const int4*)w_lds + (ks * 4 + qp) * 64 + 32 * wo;
            a0.i4 = wq[n];
            a1.i4 = wq[16 + n];
            #pragma unroll
            for (int r = 0; r < 8; ++r) {
                AB bf;
                int s = r >> 1;
                if ((r & 1) == 0) {
                    bf.i[0] = D[s]; bf.i[1] = D[s + 1]; bf.i[2] = D[s + 2]; bf.i[3] = D[s + 3];
                } else {
                    #pragma unroll
                    for (int d = 0; d < 4; ++d)
                        bf.i[d] = (int)(((unsigned)D[s + d] >> 16) | ((unsigned)D[s + d + 1] << 16));
                }
                acc[0][r] = __builtin_amdgcn_mfma_f32_16x16x32_bf16(a0.v, bf.v, acc[0][r], 0, 0, 0);
                acc[1][r] = __builtin_amdgcn_mfma_f32_16x16x32_bf16(a1.v, bf.v, acc[1][r], 0, 0, 0);
            }
        }

        // per-chunk register max
        #pragma unroll
        for (int ot = 0; ot < 2; ++ot)
            #pragma unroll
            for (int rg = 0; rg < 4; ++rg) {
                float mm = m2[ot][rg];
                #pragma unroll
                for (int r = 0; r < 8; ++r) mm = fmaxf(mm, acc[ot][r][rg]);
                m2[ot][rg] = mm;
            }
    }

    // cross-lane max over n -> wt-pair combine -> dump
    #pragma unroll
    for (int s = 1; s <= 8; s <<= 1)
        #pragma unroll
        for (int ot = 0; ot < 2; ++ot)
            #pragma unroll
            for (int rg = 0; rg < 4; ++rg)
                m2[ot][rg] = fmaxf(m2[ot][rg], __shfl_xor(m2[ot][rg], s, 64));

    if (wt == 1 && n == 0) {
        #pragma unroll
        for (int ot = 0; ot < 2; ++ot)
            #pragma unroll
            for (int rg = 0; rg < 4; ++rg)
                mred[32 * wo + 16 * ot + 4 * qp + rg] = m2[ot][rg];
    }
    __syncthreads();
    if (wt == 0 && n == 0) {
        #pragma unroll
        for (int ot = 0; ot < 2; ++ot)
            #pragma unroll
            for (int rg = 0; rg < 4; ++rg) {
                int oi = 32 * wo + 16 * ot + 4 * qp + rg;
                float v = fmaxf(m2[ot][rg], mred[oi]);
                partial[((size_t)(b * GX + tcx) * 2 + ob) * 64 + oi] = v;
            }
    }
}

// max over the 16 tcx chunks, scale by -2
__global__ __launch_bounds__(256) void reduce_kernel(const float* __restrict__ partial,
                                                     float* __restrict__ out) {
    int idx = blockIdx.x * 256 + threadIdx.x;   // 4096 = 32*128
    int b = idx >> 7, o = idx & 127;
    const float* pp = partial + ((size_t)b * GX * 2 + (o >> 6)) * 64 + (o & 63);
    float mx = -FLT_MAX;
    #pragma unroll
    for (int t = 0; t < GX; ++t) mx = fmaxf(mx, pp[(size_t)t * 128]);
    out[idx] = -2.f * mx;
}

extern "C" void kernel_launch(void* const* d_in, const int* in_sizes, int n_in,
                              void* d_out, int out_size, void* d_ws, size_t ws_size,
                              hipStream_t stream) {
    const float* x = (const float*)d_in[0];   // [32][3][8192]
    const float* w = (const float*)d_in[1];   // [128][3][64]
    float* out = (float*)d_out;               // [32][128]

    // ws: wswz bf16 swizzled [3072 x 16B] | wn f32 [128] | partial f32 [32][16][2][64]
    unsigned short* wswz = (unsigned short*)d_ws;
    float* wn = (float*)((char*)d_ws + 49152);
    float* partial = (float*)((char*)d_ws + 49664);

    prep_kernel<<<13, 256, 0, stream>>>(w, wswz, wn);
    dim3 grid(GX, 2, BB);                     // 1024 blocks, 2 chunks each
    shapeconv_main<<<grid, 256, 0, stream>>>(x, wswz, wn, partial);
    reduce_kernel<<<16, 256, 0, stream>>>(partial, out);
}